// Round 5
// baseline (121.332 us; speedup 1.0000x reference)
//
#include <hip/hip_runtime.h>

// Problem constants
#define NVEC 65536      // B*R*C = 8*16*512
#define KDIM 64
#define SDIM 512

// Output layout (flat float32)
#define Z_OFF       4194304     // NVEC*KDIM
#define LCOMMIT_OFF 4259840
#define LCODE_OFF   4259841
#define E_OFF       4259842

typedef _Float16 half8   __attribute__((ext_vector_type(8)));
typedef float    floatx16 __attribute__((ext_vector_type(16)));

// Single fused kernel. 512 blocks x 256 threads (4 waves); each wave owns 32
// vectors (M=32). Block stages 4 B-tiles (128 codewords each) from c_sum into
// LDS, converting f32 -> split hi/lo f16 in the R4-verified chunk layout:
//   half addr = sub*4096 + prec*2048 + q*512 + h*256 + n*8 + j
// so the compute-side read is lane-linear: bb = cw + sub*4096 + lane*8,
// bh at +q*512, bl at +2048+q*512 (16B stride, conflict-free).
__global__ __launch_bounds__(256, 2) void vq_all(const float* __restrict__ vecs,
                                                 const float* __restrict__ c_sum,
                                                 const float* __restrict__ c_count,
                                                 float* __restrict__ out) {
    __shared__ __align__(16) _Float16 cw[16384];   // 32 KB B-tile (128 cw, hi+lo)
    __shared__ float cnL[128];
    __shared__ float vnL[4][32];
    __shared__ int   zL[4][32];

    const int tx   = threadIdx.x;
    const int lane = tx & 63;
    const int w    = tx >> 6;
    const int col  = lane & 31;
    const int h    = lane >> 5;
    const int wvec = (int)blockIdx.x * 128 + w * 32;

    if (blockIdx.x == 0 && tx == 0) out[LCODE_OFF] = 0.0f;  // l_codebook == 0 fwd

    // ---- A fragments (hi/lo f16) + vnorm, exact R4 tree ----
    half8 ahi[4], alo[4];
    float vnp = 0.0f;
    const float* arow = vecs + (size_t)(wvec + col) * KDIM + h * 8;
    #pragma unroll
    for (int q = 0; q < 4; ++q) {
        float4 x0 = *(const float4*)(arow + q * 16);
        float4 x1 = *(const float4*)(arow + q * 16 + 4);
        #define CVT(X, J) { float xx = (X); _Float16 hi5 = (_Float16)xx; \
                            float hf = (float)hi5; ahi[q][J] = hi5; \
                            alo[q][J] = (_Float16)(xx - hf); vnp += xx * xx; }
        CVT(x0.x, 0) CVT(x0.y, 1) CVT(x0.z, 2) CVT(x0.w, 3)
        CVT(x1.x, 4) CVT(x1.y, 5) CVT(x1.z, 6) CVT(x1.w, 7)
        #undef CVT
    }
    vnp += __shfl_xor(vnp, 32);
    if (h == 0) vnL[w][col] = vnp;

    // running argmax of m = -cn/2 + dot  (equiv. argmin of dist, first-index ties)
    float bm[16];
    int   bi[16];
    #pragma unroll
    for (int r = 0; r < 16; ++r) { bm[r] = -3.4e38f; bi[r] = 0; }

    // staging thread assignment: thread covers codeword cwl, k in [kh, kh+32)
    const int cwl   = tx >> 1;          // 0..127 local codeword
    const int sub_s = cwl >> 5;
    const int n_s   = cwl & 31;
    const int kh    = (tx & 1) * 32;
    const int qbase = kh >> 4;

    for (int t = 0; t < 4; ++t) {
        __syncthreads();
        // ---- stage + convert B-tile t (and cnorm) ----
        {
            int s = t * 128 + cwl;
            float inv = 1.0f / fmaxf(c_count[s], 0.01f);
            const float4* rv = (const float4*)(c_sum + (size_t)s * KDIM + kh);
            float sq = 0.0f;
            #pragma unroll
            for (int g = 0; g < 4; ++g) {        // g = (q-sel<<1)|h : one 8-elem chunk
                float4 u0 = rv[g * 2];
                float4 u1 = rv[g * 2 + 1];
                half8 hv, lv;
                #define STG(X, J) { float xx = (X) * inv; sq += xx * xx; \
                                    _Float16 hi5 = (_Float16)xx; hv[J] = hi5; \
                                    lv[J] = (_Float16)(xx - (float)hi5); }
                STG(u0.x, 0) STG(u0.y, 1) STG(u0.z, 2) STG(u0.w, 3)
                STG(u1.x, 4) STG(u1.y, 5) STG(u1.z, 6) STG(u1.w, 7)
                #undef STG
                int q    = qbase + (g >> 1);
                int hh   = g & 1;
                int base = sub_s * 4096 + q * 512 + hh * 256 + n_s * 8;
                *(half8*)(cw + base)        = hv;   // prec hi
                *(half8*)(cw + base + 2048) = lv;   // prec lo
            }
            sq += __shfl_xor(sq, 1);              // partner thread has other 32 k
            if ((tx & 1) == 0) cnL[cwl] = sq;
        }
        __syncthreads();

        // ---- compute: 4 sub-tiles of 32 codewords ----
        #pragma unroll
        for (int sub = 0; sub < 4; ++sub) {
            const _Float16* bb = cw + sub * 4096 + lane * 8;
            float ci = -0.5f * cnL[sub * 32 + col];
            floatx16 a0, a1;
            #pragma unroll
            for (int r = 0; r < 16; ++r) { a0[r] = ci; a1[r] = 0.0f; }
            #pragma unroll
            for (int q = 0; q < 4; ++q) {
                half8 bh = *(const half8*)(bb + q * 512);
                half8 bl = *(const half8*)(bb + 2048 + q * 512);
                a0 = __builtin_amdgcn_mfma_f32_32x32x16_f16(ahi[q], bh, a0, 0, 0, 0);
                a1 = __builtin_amdgcn_mfma_f32_32x32x16_f16(alo[q], bh, a1, 0, 0, 0);
                a1 = __builtin_amdgcn_mfma_f32_32x32x16_f16(ahi[q], bl, a1, 0, 0, 0);
            }
            int n = t * 128 + sub * 32 + col;
            #pragma unroll
            for (int r = 0; r < 16; ++r) {
                float m = a0[r] + a1[r];
                if (m > bm[r]) { bm[r] = m; bi[r] = n; }   // strict >, increasing n
            }
        }
    }

    // ---- cross-lane argmax per row (32 cols; xor<=16 stays in half) ----
    #pragma unroll
    for (int r = 0; r < 16; ++r) {
        float v = bm[r]; int i = bi[r];
        #pragma unroll
        for (int off = 16; off > 0; off >>= 1) {
            float ov = __shfl_xor(v, off);
            int   oi = __shfl_xor(i, off);
            if (ov > v || (ov == v && oi < i)) { v = ov; i = oi; }
        }
        bm[r] = v; bi[r] = i;
    }

    if (col == 0) {
        float esum = 0.0f;
        #pragma unroll
        for (int r = 0; r < 16; ++r) {
            int row = (r & 3) + 8 * (r >> 2) + 4 * h;   // C/D row map (R4-verified)
            int vid = wvec + row;
            float err = fmaxf(vnL[w][row] - 2.0f * bm[r], 0.0f);
            out[Z_OFF + vid] = (float)bi[r];
            out[E_OFF + vid] = err;
            zL[w][row] = bi[r];
            esum += err;
        }
        // lands on 0xAA poison = -3.03e-13: negligible vs tolerance
        atomicAdd(out + LCOMMIT_OFF, esum * (1.0f / (float)NVEC));
    }

    // ---- vecs_hat: recompute codeword rows from c_sum (no prep pass) ----
    #pragma unroll
    for (int it = 0; it < 8; ++it) {
        int row = it * 4 + (lane >> 4);
        int c4  = lane & 15;
        int z   = zL[w][row];
        float inv = 1.0f / fmaxf(c_count[z], 0.01f);
        float4 s4 = *(const float4*)(c_sum + (size_t)z * KDIM + c4 * 4);
        float4 val;
        val.x = s4.x * inv; val.y = s4.y * inv; val.z = s4.z * inv; val.w = s4.w * inv;
        *(float4*)(out + (size_t)(wvec + row) * KDIM + c4 * 4) = val;
    }
}

extern "C" void kernel_launch(void* const* d_in, const int* in_sizes, int n_in,
                              void* d_out, int out_size, void* d_ws, size_t ws_size,
                              hipStream_t stream) {
    const float* vecs    = (const float*)d_in[0];  // [8,16,512,64]
    const float* c_sum   = (const float*)d_in[1];  // [512,64]
    const float* c_count = (const float*)d_in[2];  // [512]
    float* out = (float*)d_out;

    vq_all<<<NVEC / 128, 256, 0, stream>>>(vecs, c_sum, c_count, out);
}

// Round 6
// 116.105 us; speedup vs baseline: 1.0450x; 1.0450x over previous
//
#include <hip/hip_runtime.h>

// Problem constants
#define NVEC 65536      // B*R*C = 8*16*512
#define KDIM 64
#define SDIM 512

// Output layout (flat float32)
#define Z_OFF       4194304     // NVEC*KDIM
#define LCOMMIT_OFF 4259840
#define LCODE_OFF   4259841
#define E_OFF       4259842

typedef _Float16 half8    __attribute__((ext_vector_type(8)));
typedef float    floatx16 __attribute__((ext_vector_type(16)));

// ws: c32 [SDIM*KDIM] f32, cnorm [SDIM] f32, cbf16 [SDIM*KDIM*2] f16
//
// cbf16 chunk layout (R4-verified): half index
//   (s>>5)*4096 + p*2048 + q*512 + h*256 + (s&31)*8 + j
// Tile t (128 codewords) = 32 KB contiguous at t*16384 halfs, and within the
// tile the layout IS the LDS compute layout -> main stages with a pure linear
// 16B-chunk DMA (global_load_lds), zero conversion, zero ds_writes.

__global__ void vq_prep(const float* __restrict__ c_sum,
                        const float* __restrict__ c_count,
                        float* __restrict__ c32,
                        float* __restrict__ cnorm,
                        _Float16* __restrict__ cbf16,
                        float* __restrict__ out) {
    int s = blockIdx.x;          // 0..511
    int k = threadIdx.x;         // 0..63
    float cnt = c_count[s];
    float inv = 1.0f / fmaxf(cnt, 0.01f);
    float x = c_sum[s * KDIM + k] * inv;
    c32[s * KDIM + k] = x;
    float sq = x * x;
    #pragma unroll
    for (int off = 32; off > 0; off >>= 1)
        sq += __shfl_down(sq, off);
    if (k == 0) cnorm[s] = sq;

    __shared__ _Float16 hb[64], lb[64];
    _Float16 hi = (_Float16)x;
    float hiF = (float)hi;
    _Float16 lo = (_Float16)(x - hiF);
    hb[k] = hi; lb[k] = lo;
    __syncthreads();
    if (k < 16) {
        int p  = k >> 3;
        int qh = k & 7;                       // q*2 + h
        int k0 = (qh >> 1) * 16 + (qh & 1) * 8;
        const _Float16* srcb = (p ? lb : hb) + k0;
        half8 v;
        #pragma unroll
        for (int j = 0; j < 8; ++j) v[j] = srcb[j];
        size_t chunk = ((size_t)(s >> 5) * 16 + p * 8 + qh) * 32 + (s & 31);
        *(half8*)(cbf16 + chunk * 8) = v;
    }
    if (s == 0 && k == 0) {
        out[LCOMMIT_OFF] = 0.0f;
        out[LCODE_OFF]   = 0.0f;
    }
}

// 512 blocks x 256 threads (4 waves, M=32/wave). Double-buffered DMA staging.
__global__ __launch_bounds__(256, 2) void vq_main(const float* __restrict__ vecs,
                                                  const _Float16* __restrict__ cbf16,
                                                  const float* __restrict__ c32,
                                                  const float* __restrict__ cnorm,
                                                  float* __restrict__ out) {
    __shared__ __align__(16) _Float16 cw[2][16384];   // 2 x 32 KB B-tiles
    __shared__ float cnL[512];
    __shared__ float vnL[4][32];
    __shared__ int   zL[4][32];

    const int tx   = threadIdx.x;
    const int lane = tx & 63;
    const int w    = tx >> 6;
    const int col  = lane & 31;
    const int h    = lane >> 5;
    const int wvec = (int)blockIdx.x * 128 + w * 32;

    // async DMA of one 32 KB tile: wave w copies bytes [w*8K, w*8K+8K)
    // as 8 instructions x (64 lanes x 16 B). LDS dest = uniform base + lane*16.
    #define DMA_TILE(buf, t)                                                      \
    {                                                                             \
        const _Float16* _src = cbf16 + (size_t)(t) * 16384 + w * 4096 + lane * 8; \
        _Float16* _dst = &cw[buf][w * 4096 + lane * 8];                           \
        _Pragma("unroll")                                                         \
        for (int _i = 0; _i < 8; ++_i)                                            \
            __builtin_amdgcn_global_load_lds(                                     \
                (const __attribute__((address_space(1))) void*)(_src + _i * 512), \
                (__attribute__((address_space(3))) void*)(_dst + _i * 512),       \
                16, 0, 0);                                                        \
    }

    DMA_TILE(0, 0)   // tile 0 in flight during the whole prologue

    // ---- A fragments (hi/lo f16) + vnorm (R4/R5-verified tree) ----
    half8 ahi[4], alo[4];
    float vnp = 0.0f;
    const float* arow = vecs + (size_t)(wvec + col) * KDIM + h * 8;
    #pragma unroll
    for (int q = 0; q < 4; ++q) {
        float4 x0 = *(const float4*)(arow + q * 16);
        float4 x1 = *(const float4*)(arow + q * 16 + 4);
        #define CVT(X, J) { float xx = (X); _Float16 hi5 = (_Float16)xx; \
                            float hf = (float)hi5; ahi[q][J] = hi5; \
                            alo[q][J] = (_Float16)(xx - hf); vnp += xx * xx; }
        CVT(x0.x, 0) CVT(x0.y, 1) CVT(x0.z, 2) CVT(x0.w, 3)
        CVT(x1.x, 4) CVT(x1.y, 5) CVT(x1.z, 6) CVT(x1.w, 7)
        #undef CVT
    }
    vnp += __shfl_xor(vnp, 32);
    if (h == 0) vnL[w][col] = vnp;

    // whole cnorm into LDS once
    cnL[tx]       = cnorm[tx];
    cnL[tx + 256] = cnorm[tx + 256];

    // running argmax of m = -cn/2 + dot (== argmin dist; first-index ties)
    float bm[16];
    int   bi[16];
    #pragma unroll
    for (int r = 0; r < 16; ++r) { bm[r] = -3.4e38f; bi[r] = 0; }

    for (int t = 0; t < 4; ++t) {
        // barrier: (a) all waves past compute on buf[(t+1)&1], (b) compiler's
        // vmcnt(0)+lgkmcnt(0) drain => DMA for tile t landed & visible.
        __syncthreads();
        if (t < 3) DMA_TILE((t + 1) & 1, t + 1)   // in flight across compute(t)

        const _Float16* cwb = cw[t & 1];
        #pragma unroll
        for (int sub = 0; sub < 4; ++sub) {
            const _Float16* bb = cwb + sub * 4096 + lane * 8;
            float ci = -0.5f * cnL[t * 128 + sub * 32 + col];
            floatx16 a0, a1;
            #pragma unroll
            for (int r = 0; r < 16; ++r) { a0[r] = ci; a1[r] = 0.0f; }
            #pragma unroll
            for (int q = 0; q < 4; ++q) {
                half8 bh = *(const half8*)(bb + q * 512);
                half8 bl = *(const half8*)(bb + 2048 + q * 512);
                a0 = __builtin_amdgcn_mfma_f32_32x32x16_f16(ahi[q], bh, a0, 0, 0, 0);
                a1 = __builtin_amdgcn_mfma_f32_32x32x16_f16(alo[q], bh, a1, 0, 0, 0);
                a1 = __builtin_amdgcn_mfma_f32_32x32x16_f16(ahi[q], bl, a1, 0, 0, 0);
            }
            int n = t * 128 + sub * 32 + col;
            #pragma unroll
            for (int r = 0; r < 16; ++r) {
                float m = a0[r] + a1[r];
                if (m > bm[r]) { bm[r] = m; bi[r] = n; }   // strict >, increasing n
            }
        }
    }

    // ---- cross-lane argmax per row (32 cols; xor<=16 stays within h) ----
    #pragma unroll
    for (int r = 0; r < 16; ++r) {
        float v = bm[r]; int i = bi[r];
        #pragma unroll
        for (int off = 16; off > 0; off >>= 1) {
            float ov = __shfl_xor(v, off);
            int   oi = __shfl_xor(i, off);
            if (ov > v || (ov == v && oi < i)) { v = ov; i = oi; }
        }
        bm[r] = v; bi[r] = i;
    }

    if (col == 0) {
        float esum = 0.0f;
        #pragma unroll
        for (int r = 0; r < 16; ++r) {
            int row = (r & 3) + 8 * (r >> 2) + 4 * h;   // C/D row map (verified)
            int vid = wvec + row;
            float err = fmaxf(vnL[w][row] - 2.0f * bm[r], 0.0f);
            out[Z_OFF + vid] = (float)bi[r];
            out[E_OFF + vid] = err;
            zL[w][row] = bi[r];
            esum += err;
        }
        atomicAdd(out + LCOMMIT_OFF, esum * (1.0f / (float)NVEC));
    }

    // ---- vecs_hat gather from c32 (R4-verified), coalesced float4 ----
    #pragma unroll
    for (int it = 0; it < 8; ++it) {
        int row = it * 4 + (lane >> 4);
        int c4  = lane & 15;
        int z   = zL[w][row];
        float4 val = *(const float4*)(c32 + (size_t)z * KDIM + c4 * 4);
        *(float4*)(out + (size_t)(wvec + row) * KDIM + c4 * 4) = val;
    }
    #undef DMA_TILE
}

extern "C" void kernel_launch(void* const* d_in, const int* in_sizes, int n_in,
                              void* d_out, int out_size, void* d_ws, size_t ws_size,
                              hipStream_t stream) {
    const float* vecs    = (const float*)d_in[0];  // [8,16,512,64]
    const float* c_sum   = (const float*)d_in[1];  // [512,64]
    const float* c_count = (const float*)d_in[2];  // [512]
    float* out = (float*)d_out;

    float*    c32   = (float*)d_ws;                      // 128 KB
    float*    cnorm = c32 + SDIM * KDIM;                 // 2 KB
    _Float16* cbf16 = (_Float16*)(cnorm + SDIM);         // 128 KB

    vq_prep<<<SDIM, KDIM, 0, stream>>>(c_sum, c_count, c32, cnorm, cbf16, out);
    vq_main<<<NVEC / 128, 256, 0, stream>>>(vecs, cbf16, c32, cnorm, out);
}

// Round 7
// 97.427 us; speedup vs baseline: 1.2454x; 1.1917x over previous
//
#include <hip/hip_runtime.h>

// Problem constants
#define NVEC 65536      // B*R*C = 8*16*512
#define KDIM 64
#define SDIM 512

// Output layout (flat float32)
#define Z_OFF       4194304     // NVEC*KDIM
#define LCOMMIT_OFF 4259840
#define LCODE_OFF   4259841
#define E_OFF       4259842

typedef _Float16 half8    __attribute__((ext_vector_type(8)));
typedef float    floatx16 __attribute__((ext_vector_type(16)));

// ws: c32 [SDIM*KDIM] f32, cnorm [SDIM] f32, cbf16 [SDIM*KDIM*2] f16
//
// cbf16 chunk layout (R4-verified): half index
//   (s>>5)*4096 + p*2048 + q*512 + h*256 + (s&31)*8 + j
// Tile t (128 codewords) = 32 KB contiguous at t*16384 halfs; within the tile
// the layout IS the LDS compute layout -> pure linear 16B DMA staging.

__global__ void vq_prep(const float* __restrict__ c_sum,
                        const float* __restrict__ c_count,
                        float* __restrict__ c32,
                        float* __restrict__ cnorm,
                        _Float16* __restrict__ cbf16,
                        float* __restrict__ out) {
    int s = blockIdx.x;          // 0..511
    int k = threadIdx.x;         // 0..63
    float cnt = c_count[s];
    float inv = 1.0f / fmaxf(cnt, 0.01f);
    float x = c_sum[s * KDIM + k] * inv;
    c32[s * KDIM + k] = x;
    float sq = x * x;
    #pragma unroll
    for (int off = 32; off > 0; off >>= 1)
        sq += __shfl_down(sq, off);
    if (k == 0) cnorm[s] = sq;

    __shared__ _Float16 hb[64], lb[64];
    _Float16 hi = (_Float16)x;
    float hiF = (float)hi;
    _Float16 lo = (_Float16)(x - hiF);
    hb[k] = hi; lb[k] = lo;
    __syncthreads();
    if (k < 16) {
        int p  = k >> 3;
        int qh = k & 7;                       // q*2 + h
        int k0 = (qh >> 1) * 16 + (qh & 1) * 8;
        const _Float16* srcb = (p ? lb : hb) + k0;
        half8 v;
        #pragma unroll
        for (int j = 0; j < 8; ++j) v[j] = srcb[j];
        size_t chunk = ((size_t)(s >> 5) * 16 + p * 8 + qh) * 32 + (s & 31);
        *(half8*)(cbf16 + chunk * 8) = v;
    }
    if (s == 0 && k == 0) {
        out[LCOMMIT_OFF] = 0.0f;
        out[LCODE_OFF]   = 0.0f;
    }
}

// 512 blocks x 256 threads (4 waves, M=32/wave). Double-buffered DMA staging.
__global__ __launch_bounds__(256, 2) void vq_main(const float* __restrict__ vecs,
                                                  const _Float16* __restrict__ cbf16,
                                                  const float* __restrict__ c32,
                                                  const float* __restrict__ cnorm,
                                                  float* __restrict__ out) {
    __shared__ __align__(16) _Float16 cw[2][16384];   // 2 x 32 KB B-tiles
    __shared__ float cnL[512];
    __shared__ float vnL[4][32];
    __shared__ int   zL[4][32];
    __shared__ float esumL[8];

    const int tx   = threadIdx.x;
    const int lane = tx & 63;
    const int w    = tx >> 6;
    const int col  = lane & 31;
    const int h    = lane >> 5;
    const int wvec = (int)blockIdx.x * 128 + w * 32;

    // async DMA of one 32 KB tile: wave w copies bytes [w*8K, w*8K+8K)
    // as 8 instructions x (64 lanes x 16 B). LDS dest = uniform base + lane*16.
    #define DMA_TILE(buf, t)                                                      \
    {                                                                             \
        const _Float16* _src = cbf16 + (size_t)(t) * 16384 + w * 4096 + lane * 8; \
        _Float16* _dst = &cw[buf][w * 4096 + lane * 8];                           \
        _Pragma("unroll")                                                         \
        for (int _i = 0; _i < 8; ++_i)                                            \
            __builtin_amdgcn_global_load_lds(                                     \
                (const __attribute__((address_space(1))) void*)(_src + _i * 512), \
                (__attribute__((address_space(3))) void*)(_dst + _i * 512),       \
                16, 0, 0);                                                        \
    }

    DMA_TILE(0, 0)   // tile 0 in flight during the whole prologue

    // ---- A fragments (hi/lo f16) + vnorm (R4/R5-verified tree) ----
    half8 ahi[4], alo[4];
    float vnp = 0.0f;
    const float* arow = vecs + (size_t)(wvec + col) * KDIM + h * 8;
    #pragma unroll
    for (int q = 0; q < 4; ++q) {
        float4 x0 = *(const float4*)(arow + q * 16);
        float4 x1 = *(const float4*)(arow + q * 16 + 4);
        #define CVT(X, J) { float xx = (X); _Float16 hi5 = (_Float16)xx; \
                            float hf = (float)hi5; ahi[q][J] = hi5; \
                            alo[q][J] = (_Float16)(xx - hf); vnp += xx * xx; }
        CVT(x0.x, 0) CVT(x0.y, 1) CVT(x0.z, 2) CVT(x0.w, 3)
        CVT(x1.x, 4) CVT(x1.y, 5) CVT(x1.z, 6) CVT(x1.w, 7)
        #undef CVT
    }
    vnp += __shfl_xor(vnp, 32);
    if (h == 0) vnL[w][col] = vnp;

    // whole cnorm into LDS once
    cnL[tx]       = cnorm[tx];
    cnL[tx + 256] = cnorm[tx + 256];

    // running argmax of m = -cn/2 + dot (== argmin dist; first-index ties)
    float bm[16];
    int   bi[16];
    #pragma unroll
    for (int r = 0; r < 16; ++r) { bm[r] = -3.4e38f; bi[r] = 0; }

    for (int t = 0; t < 4; ++t) {
        // barrier: (a) all waves past compute on buf[(t+1)&1], (b) compiler's
        // vmcnt(0)+lgkmcnt(0) drain => DMA for tile t landed & visible.
        __syncthreads();
        if (t < 3) DMA_TILE((t + 1) & 1, t + 1)   // in flight across compute(t)

        const _Float16* cwb = cw[t & 1];
        #pragma unroll
        for (int sub = 0; sub < 4; ++sub) {
            const _Float16* bb = cwb + sub * 4096 + lane * 8;
            float ci = -0.5f * cnL[t * 128 + sub * 32 + col];
            floatx16 a0, a1;
            #pragma unroll
            for (int r = 0; r < 16; ++r) { a0[r] = ci; a1[r] = 0.0f; }
            #pragma unroll
            for (int q = 0; q < 4; ++q) {
                half8 bh = *(const half8*)(bb + q * 512);
                half8 bl = *(const half8*)(bb + 2048 + q * 512);
                a0 = __builtin_amdgcn_mfma_f32_32x32x16_f16(ahi[q], bh, a0, 0, 0, 0);
                a1 = __builtin_amdgcn_mfma_f32_32x32x16_f16(alo[q], bh, a1, 0, 0, 0);
                a1 = __builtin_amdgcn_mfma_f32_32x32x16_f16(ahi[q], bl, a1, 0, 0, 0);
            }
            int n = t * 128 + sub * 32 + col;
            #pragma unroll
            for (int r = 0; r < 16; ++r) {
                float m = a0[r] + a1[r];
                if (m > bm[r]) { bm[r] = m; bi[r] = n; }   // strict >, increasing n
            }
        }
    }

    // ---- cross-lane argmax per row (32 cols; xor<=16 stays within h) ----
    #pragma unroll
    for (int r = 0; r < 16; ++r) {
        float v = bm[r]; int i = bi[r];
        #pragma unroll
        for (int off = 16; off > 0; off >>= 1) {
            float ov = __shfl_xor(v, off);
            int   oi = __shfl_xor(i, off);
            if (ov > v || (ov == v && oi < i)) { v = ov; i = oi; }
        }
        bm[r] = v; bi[r] = i;
    }

    if (col == 0) {
        float esum = 0.0f;
        #pragma unroll
        for (int r = 0; r < 16; ++r) {
            int row = (r & 3) + 8 * (r >> 2) + 4 * h;   // C/D row map (verified)
            int vid = wvec + row;
            float err = fmaxf(vnL[w][row] - 2.0f * bm[r], 0.0f);
            out[Z_OFF + vid] = (float)bi[r];
            out[E_OFF + vid] = err;
            zL[w][row] = bi[r];
            esum += err;
        }
        esumL[w * 2 + h] = esum;   // R7: stash partial, no global atomic here
    }

    // ---- vecs_hat gather from c32 (R4-verified), coalesced float4 ----
    #pragma unroll
    for (int it = 0; it < 8; ++it) {
        int row = it * 4 + (lane >> 4);
        int c4  = lane & 15;
        int z   = zL[w][row];
        float4 val = *(const float4*)(c32 + (size_t)z * KDIM + c4 * 4);
        *(float4*)(out + (size_t)(wvec + row) * KDIM + c4 * 4) = val;
    }

    // ---- R7 single change: ONE same-address atomic per block, not 8 ----
    // R4/R5/R6 all pinned at ~60 us == 4096 serialized same-line RMWs at the
    // owning L2 slice (~35 cyc each). 512 blocks x 1 atomic hides the drain.
    __syncthreads();
    if (tx == 0) {
        float tot = esumL[0] + esumL[1] + esumL[2] + esumL[3]
                  + esumL[4] + esumL[5] + esumL[6] + esumL[7];
        atomicAdd(out + LCOMMIT_OFF, tot * (1.0f / (float)NVEC));
    }
    #undef DMA_TILE
}

extern "C" void kernel_launch(void* const* d_in, const int* in_sizes, int n_in,
                              void* d_out, int out_size, void* d_ws, size_t ws_size,
                              hipStream_t stream) {
    const float* vecs    = (const float*)d_in[0];  // [8,16,512,64]
    const float* c_sum   = (const float*)d_in[1];  // [512,64]
    const float* c_count = (const float*)d_in[2];  // [512]
    float* out = (float*)d_out;

    float*    c32   = (float*)d_ws;                      // 128 KB
    float*    cnorm = c32 + SDIM * KDIM;                 // 2 KB
    _Float16* cbf16 = (_Float16*)(cnorm + SDIM);         // 128 KB

    vq_prep<<<SDIM, KDIM, 0, stream>>>(c_sum, c_count, c32, cnorm, cbf16, out);
    vq_main<<<NVEC / 128, 256, 0, stream>>>(vecs, cbf16, c32, cnorm, out);
}